// Round 5
// baseline (294.074 us; speedup 1.0000x reference)
//
#include <hip/hip_runtime.h>

#define NN 2048
#define CC 768
#define HH 12
#define SCALE2 0.18033688011112042f   /* 0.125 * log2(e) */
#define NEGB  -3.0e35f
#define THR   12.0f                    /* defer-max threshold, log2 domain */

typedef __attribute__((ext_vector_type(4))) float f32x4;
typedef __attribute__((ext_vector_type(8))) short short8;
typedef __attribute__((ext_vector_type(8))) unsigned short u16x8;

#if __has_builtin(__builtin_amdgcn_exp2f)
#define EXP2(x) __builtin_amdgcn_exp2f(x)
#else
#define EXP2(x) exp2f(x)
#endif

static __device__ __forceinline__ unsigned short f2bf(float f) {
    unsigned u = __float_as_uint(f);
    u += 0x7FFFu + ((u >> 16) & 1u);   // RNE
    return (unsigned short)(u >> 16);
}

static __device__ __forceinline__ f32x4 MFMA(u16x8 a, u16x8 b, f32x4 c) {
    union { u16x8 u; short8 s; } ua, ub;
    ua.u = a; ub.u = b;
    return __builtin_amdgcn_mfma_f32_16x16x32_bf16(ua.s, ub.s, c, 0, 0, 0);
}

static __device__ __forceinline__ void glds16(const void* g, void* l) {
    __builtin_amdgcn_global_load_lds(
        (const __attribute__((address_space(1))) unsigned int*)g,
        (__attribute__((address_space(3))) unsigned int*)l, 16, 0, 0);
}

// ---------------- f32 -> bf16 convert ----------------
__global__ void cvt_f32_bf16(const float* __restrict__ in,
                             unsigned short* __restrict__ out, int n8) {
    int i = blockIdx.x * blockDim.x + threadIdx.x;
    if (i >= n8) return;
    const f32x4* p = (const f32x4*)(in + (size_t)i * 8);
    f32x4 a = p[0], b = p[1];
    u16x8 o;
    o[0] = f2bf(a[0]); o[1] = f2bf(a[1]); o[2] = f2bf(a[2]); o[3] = f2bf(a[3]);
    o[4] = f2bf(b[0]); o[5] = f2bf(b[1]); o[6] = f2bf(b[2]); o[7] = f2bf(b[3]);
    *(u16x8*)(out + (size_t)i * 8) = o;
}

// ---------------- GEMM: C[M][N] = A[MxK] * Bt[NxK]^T ----------------
__launch_bounds__(256)
__global__ void gemm_bt(const unsigned short* __restrict__ A,
                        const unsigned short* __restrict__ Bt,
                        unsigned short* __restrict__ outB,
                        float* __restrict__ outF,
                        const float* __restrict__ bias,
                        int M, int N, int K, int qcols) {
    __shared__ __align__(16) unsigned short As[128][64];
    __shared__ __align__(16) unsigned short Bs[128][64];
    int tid = threadIdx.x, lane = tid & 63, w = tid >> 6;
    int wm = w >> 1, wn = w & 1;
    int li = lane & 15, g = lane >> 4;
    int bn = blockIdx.x, bm = blockIdx.y;

    f32x4 acc[4][4] = {};

    int lrow = lane >> 3, lsl = lane & 7;
    int xcol = (lsl ^ (lrow & 7)) * 8;          // pre-swizzled source column
    const unsigned short* Ag = A  + (size_t)(bm * 128 + w * 32 + lrow) * K + xcol;
    const unsigned short* Bg = Bt + (size_t)(bn * 128 + w * 32 + lrow) * K + xcol;

    for (int k0 = 0; k0 < K; k0 += 64) {
        __syncthreads();
#pragma unroll
        for (int i = 0; i < 4; ++i) {
            glds16(Ag + (size_t)(i * 8) * K + k0, &As[w * 32 + i * 8][0]);
            glds16(Bg + (size_t)(i * 8) * K + k0, &Bs[w * 32 + i * 8][0]);
        }
        __syncthreads();
#pragma unroll
        for (int kk = 0; kk < 2; ++kk) {
            u16x8 af[4], bf[4];
#pragma unroll
            for (int mi = 0; mi < 4; ++mi)
                af[mi] = *(const u16x8*)&As[wm * 64 + mi * 16 + li][((4 * kk + g) ^ (li & 7)) * 8];
#pragma unroll
            for (int ni = 0; ni < 4; ++ni)
                bf[ni] = *(const u16x8*)&Bs[wn * 64 + ni * 16 + li][((4 * kk + g) ^ (li & 7)) * 8];
            __builtin_amdgcn_s_setprio(1);
#pragma unroll
            for (int mi = 0; mi < 4; ++mi)
#pragma unroll
                for (int ni = 0; ni < 4; ++ni)
                    acc[mi][ni] = MFMA(af[mi], bf[ni], acc[mi][ni]);
            __builtin_amdgcn_s_setprio(0);
        }
    }

#pragma unroll
    for (int mi = 0; mi < 4; ++mi) {
#pragma unroll
        for (int ni = 0; ni < 4; ++ni) {
#pragma unroll
            for (int r = 0; r < 4; ++r) {
                int row = bm * 128 + wm * 64 + mi * 16 + g * 4 + r;
                int col = bn * 128 + wn * 64 + ni * 16 + li;
                float v = acc[mi][ni][r];
                if (outB) {
                    if (col < qcols) v *= SCALE2;
                    outB[(size_t)row * N + col] = f2bf(v);
                } else {
                    outF[(size_t)row * N + col] = v + bias[col];
                }
            }
        }
    }
}

// ---------------- masked flash attention ----------------
// 256 thr / 4 waves / 16 q-rows per wave (12 waves/CU).  KVBLK=128 per
// barrier (16 iterations).  K is read directly from global in MFMA fragment
// layout (L2-resident per head, XCD swizzle keeps a head on one XCD).
// V double-buffered in LDS (reg-staged one tile ahead, written at iter top).
// Dropped query rows: zeroed Q + suppressed penalties -> uniform softmax ->
// output = mean of V (matches reference exactly).
__launch_bounds__(256, 3)
__global__ void attn_kernel(const unsigned short* __restrict__ qkv,
                            const int* __restrict__ mask,
                            unsigned short* __restrict__ hout) {
    __shared__ __align__(16) unsigned int Vp[2][2][64][32];
    __shared__ __align__(16) float pen[NN];

    int tid = threadIdx.x;
    int lane = tid & 63;
    int w = tid >> 6;                  // 0..3
    int li = lane & 15, g = lane >> 4;

    // XCD-chunked swizzle: one head's q-blocks stay on one XCD
    int lb = (blockIdx.x & 7) * 96 + (blockIdx.x >> 3);
    int qb = lb & 31;
    int bh = lb >> 5;
    int b = bh / HH, head = bh % HH;
    const int* mb = mask + b * NN;

    {   // penalty table: pen[j] = keep ? 0 : NEGB   (256 thr x 8)
        int i = tid * 8;
        union { int4 v; int a[4]; } m0, m1;
        m0.v = *(const int4*)&mb[i];
        m1.v = *(const int4*)&mb[i + 4];
        f32x4 p0, p1;
#pragma unroll
        for (int r = 0; r < 4; ++r) {
            p0[r] = m0.a[r] ? 0.f : NEGB;
            p1[r] = m1.a[r] ? 0.f : NEGB;
        }
        *(f32x4*)&pen[i] = p0;
        *(f32x4*)&pen[i + 4] = p1;
    }

    const unsigned short* qbase = qkv + (size_t)(b * NN) * 2304;

    // Q fragments (k-mapping: d = 32*kk + 8*g + e, consistent across A/B)
    int qrow = qb * 64 + w * 16 + li;
    const unsigned short* qp = qbase + (size_t)qrow * 2304 + head * 64;
    u16x8 qf0 = *(const u16x8*)(qp + g * 8);
    u16x8 qf1 = *(const u16x8*)(qp + 32 + g * 8);
    bool rk = mb[qrow] != 0;
    float pm = rk ? 1.f : 0.f;
    if (!rk) { qf0 = (u16x8)0; qf1 = (u16x8)0; }   // dropped query -> logits 0

    // K per-lane fragment base (row li within j-tile, d-chunk 8g)
    const unsigned short* kp = qbase + CC + head * 64 + (size_t)li * 2304 + g * 8;

    // V staging: thread covers rows 4a..4a+3 of the 128-row tile, d-chunk 8
    int a4 = tid >> 3;                 // 0..31
    int vkc = (tid & 7) * 8;
    int sub = a4 >> 4;                 // 64-row subtile
    int jp0 = (2 * a4) & 31, jp1 = jp0 + 1;
    int vca = (jp0 & 16) | ((jp0 & 6) << 1) | ((jp0 & 8) >> 2) | (jp0 & 1);
    int vcb = (jp1 & 16) | ((jp1 & 6) << 1) | ((jp1 & 8) >> 2) | (jp1 & 1);
    const unsigned short* vg = qbase + 2 * CC + head * 64 + vkc;

    u16x8 vr0, vr1, vr2, vr3;
    auto loadV = [&](int kb) {
        const unsigned short* p = vg + (size_t)(kb + 4 * a4) * 2304;
        vr0 = *(const u16x8*)(p);
        vr1 = *(const u16x8*)(p + 2304);
        vr2 = *(const u16x8*)(p + 2 * 2304);
        vr3 = *(const u16x8*)(p + 3 * 2304);
    };
    auto writeV = [&](int buf) {
        union { u16x8 v; unsigned u[4]; } a0, a1, a2, a3;
        a0.v = vr0; a1.v = vr1; a2.v = vr2; a3.v = vr3;
        unsigned* vp = &Vp[buf][sub][0][0];
#pragma unroll
        for (int e = 0; e < 8; ++e) {
            int dd = (e + (tid & 7)) & 7;          // lane-staggered write order
            int d0 = vkc + dd;
            unsigned dwa = __builtin_amdgcn_perm(a1.u[dd >> 1], a0.u[dd >> 1],
                                                 (dd & 1) ? 0x07060302u : 0x05040100u);
            unsigned dwb = __builtin_amdgcn_perm(a3.u[dd >> 1], a2.u[dd >> 1],
                                                 (dd & 1) ? 0x07060302u : 0x05040100u);
            vp[d0 * 32 + (((vca >> 2) ^ (d0 & 7)) << 2) + (vca & 3)] = dwa;
            vp[d0 * 32 + (((vcb >> 2) ^ (d0 & 7)) << 2) + (vcb & 3)] = dwb;
        }
    };

    // prologue: tile0 -> LDS, tile1 -> regs
    loadV(0);
    writeV(0);
    loadV(128);

    float m_st = -1e30f, l_st = 0.f;
    f32x4 acc[4] = {};

    for (int it = 0; it < 16; ++it) {
        __syncthreads();
        int cur = it & 1, nx = cur ^ 1;
        int kb = it * 128;
        if (it < 15) writeV(nx);
        if (it < 14) loadV(kb + 256);

        // ---- K fragments direct from global (L2-resident) ----
        u16x8 kf[8][2];
#pragma unroll
        for (int t = 0; t < 8; ++t) {
            const unsigned short* kr = kp + (size_t)(kb + t * 16) * 2304;
            kf[t][0] = *(const u16x8*)(kr);
            kf[t][1] = *(const u16x8*)(kr + 32);
        }

        // ---- S^T: K * Q^T ----
        f32x4 st[8];
        __builtin_amdgcn_s_setprio(1);
#pragma unroll
        for (int t = 0; t < 8; ++t) {
            f32x4 z = {};
            z = MFMA(kf[t][0], qf0, z);
            z = MFMA(kf[t][1], qf1, z);
            st[t] = z;
        }
        __builtin_amdgcn_s_setprio(0);

        // ---- masked online softmax (base-2), defer-max ----
        const float* pp = &pen[kb];
        float lmax = -3e38f;
#pragma unroll
        for (int t = 0; t < 8; ++t) {
            f32x4 p4 = *(const f32x4*)&pp[t * 16 + g * 4];
            st[t] += p4 * pm;
            lmax = fmaxf(lmax, fmaxf(fmaxf(st[t][0], st[t][1]),
                                     fmaxf(st[t][2], st[t][3])));
        }
        if (__any(lmax > m_st + THR)) {
            float tm = lmax;
            tm = fmaxf(tm, __shfl_xor(tm, 16));
            tm = fmaxf(tm, __shfl_xor(tm, 32));
            float mnew = fmaxf(m_st, tm);
            float alpha = EXP2(m_st - mnew);
            float ar[4];
#pragma unroll
            for (int r = 0; r < 4; ++r) ar[r] = __shfl(alpha, g * 4 + r);
#pragma unroll
            for (int dt = 0; dt < 4; ++dt)
#pragma unroll
                for (int r = 0; r < 4; ++r) acc[dt][r] *= ar[r];
            l_st *= alpha;
            m_st = mnew;
        }
        float lsum = 0.f;
        union { unsigned u[8]; u16x8 v[2]; } pu[2];
#pragma unroll
        for (int s = 0; s < 2; ++s)
#pragma unroll
            for (int t = 0; t < 4; ++t) {
                f32x4 e4;
#pragma unroll
                for (int r = 0; r < 4; ++r) {
                    e4[r] = EXP2(st[s * 4 + t][r] - m_st);
                    lsum += e4[r];
                }
                pu[s].u[t * 2]     = __builtin_amdgcn_perm(__float_as_uint(e4[1]),
                                                           __float_as_uint(e4[0]), 0x07060302u);
                pu[s].u[t * 2 + 1] = __builtin_amdgcn_perm(__float_as_uint(e4[3]),
                                                           __float_as_uint(e4[2]), 0x07060302u);
            }
        lsum += __shfl_xor(lsum, 16);
        lsum += __shfl_xor(lsum, 32);
        l_st += lsum;

        // ---- PV over both 64-row subtiles ----
        __builtin_amdgcn_s_setprio(1);
#pragma unroll
        for (int s = 0; s < 2; ++s)
#pragma unroll
            for (int h = 0; h < 2; ++h)
#pragma unroll
                for (int dt = 0; dt < 4; ++dt) {
                    const unsigned* vr = &Vp[cur][s][dt * 16 + li][0];
                    u16x8 vf = *(const u16x8*)(vr + (((4 * h + g) ^ (li & 7)) << 2));
                    acc[dt] = MFMA(pu[s].v[h], vf, acc[dt]);
                }
        __builtin_amdgcn_s_setprio(0);
    }

    // ---- epilogue ----
    float linv = 1.0f / l_st;
    float lr[4];
#pragma unroll
    for (int r = 0; r < 4; ++r) lr[r] = __shfl(linv, g * 4 + r);
    size_t obase = ((size_t)(b * NN + qb * 64 + w * 16)) * CC + head * 64;
#pragma unroll
    for (int dt = 0; dt < 4; ++dt)
#pragma unroll
        for (int r = 0; r < 4; ++r)
            hout[obase + (size_t)(g * 4 + r) * CC + dt * 16 + li] =
                f2bf(acc[dt][r] * lr[r]);
}

extern "C" void kernel_launch(void* const* d_in, const int* in_sizes, int n_in,
                              void* d_out, int out_size, void* d_ws, size_t ws_size,
                              hipStream_t stream) {
    const float* x     = (const float*)d_in[0];
    const int*   mask  = (const int*)d_in[1];
    const float* wqkv  = (const float*)d_in[2];
    const float* wproj = (const float*)d_in[3];
    const float* bproj = (const float*)d_in[4];
    float* out = (float*)d_out;

    unsigned short* x_bf     = (unsigned short*)d_ws;          // 4096*768
    unsigned short* wqkv_bf  = x_bf + 3145728;                 // 2304*768
    unsigned short* wproj_bf = wqkv_bf + 1769472;              // 768*768
    unsigned short* qkv_bf   = wproj_bf + 589824;              // 4096*2304
    unsigned short* h_bf     = qkv_bf + 9437184;               // 4096*768

    cvt_f32_bf16<<<1536, 256, 0, stream>>>(x, x_bf, 393216);
    cvt_f32_bf16<<<864, 256, 0, stream>>>(wqkv, wqkv_bf, 221184);
    cvt_f32_bf16<<<288, 256, 0, stream>>>(wproj, wproj_bf, 73728);

    // qkv = x @ w_qkv^T -> bf16 (Q columns pre-scaled by SCALE*log2e)
    gemm_bt<<<dim3(18, 32), 256, 0, stream>>>(x_bf, wqkv_bf, qkv_bf, nullptr,
                                              nullptr, 4096, 2304, 768, 768);
    // masked flash attention -> h (B,N,C) bf16
    attn_kernel<<<768, 256, 0, stream>>>(qkv_bf, mask, h_bf);
    // out = h @ w_proj^T + b -> f32
    gemm_bt<<<dim3(6, 32), 256, 0, stream>>>(h_bf, wproj_bf, nullptr, out,
                                             bproj, 4096, 768, 768, 0);
}

// Round 6
// 224.132 us; speedup vs baseline: 1.3121x; 1.3121x over previous
//
#include <hip/hip_runtime.h>

#define NN 2048
#define CC 768
#define HH 12
#define SCALE2 0.18033688011112042f   /* 0.125 * log2(e) */
#define NEGB  -3.0e35f
#define THR   12.0f                    /* defer-max threshold, log2 domain */

typedef __attribute__((ext_vector_type(4))) float f32x4;
typedef __attribute__((ext_vector_type(8))) short short8;
typedef __attribute__((ext_vector_type(8))) unsigned short u16x8;

#if __has_builtin(__builtin_amdgcn_exp2f)
#define EXP2(x) __builtin_amdgcn_exp2f(x)
#else
#define EXP2(x) exp2f(x)
#endif

static __device__ __forceinline__ unsigned short f2bf(float f) {
    unsigned u = __float_as_uint(f);
    u += 0x7FFFu + ((u >> 16) & 1u);   // RNE
    return (unsigned short)(u >> 16);
}

static __device__ __forceinline__ f32x4 MFMA(u16x8 a, u16x8 b, f32x4 c) {
    union { u16x8 u; short8 s; } ua, ub;
    ua.u = a; ub.u = b;
    return __builtin_amdgcn_mfma_f32_16x16x32_bf16(ua.s, ub.s, c, 0, 0, 0);
}

static __device__ __forceinline__ void glds16(const void* g, void* l) {
    __builtin_amdgcn_global_load_lds(
        (const __attribute__((address_space(1))) unsigned int*)g,
        (__attribute__((address_space(3))) unsigned int*)l, 16, 0, 0);
}

// ---------------- f32 -> bf16 convert ----------------
__global__ void cvt_f32_bf16(const float* __restrict__ in,
                             unsigned short* __restrict__ out, int n8) {
    int i = blockIdx.x * blockDim.x + threadIdx.x;
    if (i >= n8) return;
    const f32x4* p = (const f32x4*)(in + (size_t)i * 8);
    f32x4 a = p[0], b = p[1];
    u16x8 o;
    o[0] = f2bf(a[0]); o[1] = f2bf(a[1]); o[2] = f2bf(a[2]); o[3] = f2bf(a[3]);
    o[4] = f2bf(b[0]); o[5] = f2bf(b[1]); o[6] = f2bf(b[2]); o[7] = f2bf(b[3]);
    *(u16x8*)(out + (size_t)i * 8) = o;
}

// ---------------- GEMM: C[M][N] = A[MxK] * Bt[NxK]^T ----------------
__launch_bounds__(256)
__global__ void gemm_bt(const unsigned short* __restrict__ A,
                        const unsigned short* __restrict__ Bt,
                        unsigned short* __restrict__ outB,
                        float* __restrict__ outF,
                        const float* __restrict__ bias,
                        int M, int N, int K, int qcols) {
    __shared__ __align__(16) unsigned short As[128][64];
    __shared__ __align__(16) unsigned short Bs[128][64];
    int tid = threadIdx.x, lane = tid & 63, w = tid >> 6;
    int wm = w >> 1, wn = w & 1;
    int li = lane & 15, g = lane >> 4;
    int bn = blockIdx.x, bm = blockIdx.y;

    f32x4 acc[4][4] = {};

    int lrow = lane >> 3, lsl = lane & 7;
    int xcol = (lsl ^ (lrow & 7)) * 8;          // pre-swizzled source column
    const unsigned short* Ag = A  + (size_t)(bm * 128 + w * 32 + lrow) * K + xcol;
    const unsigned short* Bg = Bt + (size_t)(bn * 128 + w * 32 + lrow) * K + xcol;

    for (int k0 = 0; k0 < K; k0 += 64) {
        __syncthreads();
#pragma unroll
        for (int i = 0; i < 4; ++i) {
            glds16(Ag + (size_t)(i * 8) * K + k0, &As[w * 32 + i * 8][0]);
            glds16(Bg + (size_t)(i * 8) * K + k0, &Bs[w * 32 + i * 8][0]);
        }
        __syncthreads();
#pragma unroll
        for (int kk = 0; kk < 2; ++kk) {
            u16x8 af[4], bf[4];
#pragma unroll
            for (int mi = 0; mi < 4; ++mi)
                af[mi] = *(const u16x8*)&As[wm * 64 + mi * 16 + li][((4 * kk + g) ^ (li & 7)) * 8];
#pragma unroll
            for (int ni = 0; ni < 4; ++ni)
                bf[ni] = *(const u16x8*)&Bs[wn * 64 + ni * 16 + li][((4 * kk + g) ^ (li & 7)) * 8];
            __builtin_amdgcn_s_setprio(1);
#pragma unroll
            for (int mi = 0; mi < 4; ++mi)
#pragma unroll
                for (int ni = 0; ni < 4; ++ni)
                    acc[mi][ni] = MFMA(af[mi], bf[ni], acc[mi][ni]);
            __builtin_amdgcn_s_setprio(0);
        }
    }

#pragma unroll
    for (int mi = 0; mi < 4; ++mi) {
#pragma unroll
        for (int ni = 0; ni < 4; ++ni) {
#pragma unroll
            for (int r = 0; r < 4; ++r) {
                int row = bm * 128 + wm * 64 + mi * 16 + g * 4 + r;
                int col = bn * 128 + wn * 64 + ni * 16 + li;
                float v = acc[mi][ni][r];
                if (outB) {
                    if (col < qcols) v *= SCALE2;
                    outB[(size_t)row * N + col] = f2bf(v);
                } else {
                    outF[(size_t)row * N + col] = v + bias[col];
                }
            }
        }
    }
}

// ---------------- masked flash attention ----------------
// R3 structure: 256 thr / 4 waves / 16 q-rows per wave / KVBLK=64 / 12
// waves/CU.  K glds-staged XOR-swizzled; V reg-staged -> packed LDS.
// New: writeV at iter top (loadV distance 2), defer-max (THR), deferred
// l-reduction (epilogue), penalty as MFMA C-init.
__launch_bounds__(256, 3)
__global__ void attn_kernel(const unsigned short* __restrict__ qkv,
                            const int* __restrict__ mask,
                            unsigned short* __restrict__ hout) {
    __shared__ __align__(16) unsigned short Ks[2][64][64];
    __shared__ __align__(16) unsigned int   Vp[2][64][32];
    __shared__ __align__(16) float pen[NN];

    int tid = threadIdx.x;
    int lane = tid & 63;
    int w = tid >> 6;
    int li = lane & 15, g = lane >> 4;

    // XCD-chunked swizzle: one head's q-blocks stay on one XCD
    int lb = (blockIdx.x & 7) * 96 + (blockIdx.x >> 3);
    int qb = lb & 31;
    int bh = lb >> 5;
    int b = bh / HH, head = bh % HH;
    const int* mb = mask + b * NN;

    {   // penalty table: pen[j] = keep ? 0 : NEGB   (256 thr x 8)
        int i = tid * 8;
        union { int4 v; int a[4]; } m0, m1;
        m0.v = *(const int4*)&mb[i];
        m1.v = *(const int4*)&mb[i + 4];
        f32x4 p0, p1;
#pragma unroll
        for (int r = 0; r < 4; ++r) {
            p0[r] = m0.a[r] ? 0.f : NEGB;
            p1[r] = m1.a[r] ? 0.f : NEGB;
        }
        *(f32x4*)&pen[i] = p0;
        *(f32x4*)&pen[i + 4] = p1;
    }

    const unsigned short* qbase = qkv + (size_t)(b * NN) * 2304;

    // Q fragments (k-mapping: d = 32*kk + 8*g + e)
    int qrow = qb * 64 + w * 16 + li;
    const unsigned short* qp = qbase + (size_t)qrow * 2304 + head * 64;
    u16x8 qf0 = *(const u16x8*)(qp + g * 8);
    u16x8 qf1 = *(const u16x8*)(qp + 32 + g * 8);
    bool rk = mb[qrow] != 0;
    float pm = rk ? 1.f : 0.f;
    if (!rk) { qf0 = (u16x8)0; qf1 = (u16x8)0; }   // dropped query -> logits 0

    // K glds lane constants (pre-swizzled source column)
    int xslot = ((lane & 7) ^ ((lane >> 3) & 7)) * 8;
    const unsigned short* kg = qbase + CC + head * 64 + xslot
                               + (size_t)(w * 16 + (lane >> 3)) * 2304;

    // V staging lane constants (thread covers jpair 2*vm, 2*vm+1)
    int vm = tid >> 3;                 // 0..31
    int vkc = (tid & 7) * 8;           // d base
    int vcol = (vm & 16) | ((vm & 6) << 1) | ((vm & 8) >> 2) | (vm & 1);
    int vslot = vcol >> 2, vsub = vcol & 3;
    const unsigned short* vg = qbase + 2 * CC + head * 64 + vkc;

    u16x8 va, vb;
    auto stageK = [&](int buf, int kb) {
        glds16(kg + (size_t)kb * 2304,       &Ks[buf][w * 16][0]);
        glds16(kg + (size_t)(kb + 8) * 2304, &Ks[buf][w * 16 + 8][0]);
    };
    auto loadV = [&](int kb) {
        va = *(const u16x8*)(vg + (size_t)(kb + 2 * vm) * 2304);
        vb = *(const u16x8*)(vg + (size_t)(kb + 2 * vm + 1) * 2304);
    };
    auto writeV = [&](int buf) {
        union { u16x8 v; unsigned u[4]; } ua, ub;
        ua.v = va; ub.v = vb;
        unsigned* vp = &Vp[buf][0][0];
#pragma unroll
        for (int e = 0; e < 8; ++e) {
            int dd = (e + (tid & 7)) & 7;          // lane-staggered write order
            unsigned dw = __builtin_amdgcn_perm(ub.u[dd >> 1], ua.u[dd >> 1],
                                                (dd & 1) ? 0x07060302u : 0x05040100u);
            int d0 = vkc + dd;
            vp[d0 * 32 + ((vslot ^ (d0 & 7)) << 2) + vsub] = dw;
        }
    };

    // prologue: tile0 staged+written, tile1 in regs
    stageK(0, 0);
    loadV(0);
    writeV(0);
    loadV(64);

    float m_st = -1e30f;
    float l_part = 0.f;                // per-lane partial; reduced in epilogue
    f32x4 acc[4] = {};

    for (int it = 0; it < 32; ++it) {
        __syncthreads();
        int cur = it & 1, nx = cur ^ 1;
        if (it < 31) { writeV(nx); stageK(nx, (it + 1) * 64); }
        if (it < 30) loadV((it + 2) * 64);

        // ---- penalties as MFMA C-init ----
        const float* pp = &pen[it * 64];
        f32x4 ci[4];
#pragma unroll
        for (int t = 0; t < 4; ++t)
            ci[t] = (*(const f32x4*)&pp[t * 16 + g * 4]) * pm;

        // ---- S^T: K * Q^T ----
        f32x4 st[4];
        __builtin_amdgcn_s_setprio(1);
#pragma unroll
        for (int t = 0; t < 4; ++t) {
            const unsigned short* kr = &Ks[cur][t * 16 + li][0];
            u16x8 k0 = *(const u16x8*)(kr + ((g ^ (li & 7)) * 8));
            u16x8 k1 = *(const u16x8*)(kr + (((4 + g) ^ (li & 7)) * 8));
            f32x4 z = ci[t];
            z = MFMA(k0, qf0, z);
            z = MFMA(k1, qf1, z);
            st[t] = z;
        }
        __builtin_amdgcn_s_setprio(0);

        // ---- online softmax (base-2), defer-max ----
        float lmax = -3e38f;
#pragma unroll
        for (int t = 0; t < 4; ++t)
            lmax = fmaxf(lmax, fmaxf(fmaxf(st[t][0], st[t][1]),
                                     fmaxf(st[t][2], st[t][3])));
        if (__any(lmax > m_st + THR)) {
            float tm = lmax;
            tm = fmaxf(tm, __shfl_xor(tm, 16));
            tm = fmaxf(tm, __shfl_xor(tm, 32));
            float mnew = fmaxf(m_st, tm);
            float alpha = EXP2(m_st - mnew);
            float ar[4];
#pragma unroll
            for (int r = 0; r < 4; ++r) ar[r] = __shfl(alpha, g * 4 + r);
#pragma unroll
            for (int dt = 0; dt < 4; ++dt)
#pragma unroll
                for (int r = 0; r < 4; ++r) acc[dt][r] *= ar[r];
            l_part *= alpha;           // alpha is lane-correct for q = li
            m_st = mnew;
        }
        union { unsigned u[8]; u16x8 v[2]; } pu;
#pragma unroll
        for (int t = 0; t < 4; ++t) {
            f32x4 e4;
#pragma unroll
            for (int r = 0; r < 4; ++r) { e4[r] = EXP2(st[t][r] - m_st); l_part += e4[r]; }
            pu.u[t * 2]     = __builtin_amdgcn_perm(__float_as_uint(e4[1]),
                                                    __float_as_uint(e4[0]), 0x07060302u);
            pu.u[t * 2 + 1] = __builtin_amdgcn_perm(__float_as_uint(e4[3]),
                                                    __float_as_uint(e4[2]), 0x07060302u);
        }

        // ---- PV ----
        __builtin_amdgcn_s_setprio(1);
#pragma unroll
        for (int h = 0; h < 2; ++h)
#pragma unroll
            for (int dt = 0; dt < 4; ++dt) {
                const unsigned* vr = &Vp[cur][dt * 16 + li][0];
                u16x8 vf = *(const u16x8*)(vr + (((4 * h + g) ^ (li & 7)) << 2));
                acc[dt] = MFMA(pu.v[h], vf, acc[dt]);
            }
        __builtin_amdgcn_s_setprio(0);
    }

    // ---- epilogue: cross-lane l reduction, normalize, store ----
    float l_st = l_part;
    l_st += __shfl_xor(l_st, 16);
    l_st += __shfl_xor(l_st, 32);
    float linv = 1.0f / l_st;
    float lr[4];
#pragma unroll
    for (int r = 0; r < 4; ++r) lr[r] = __shfl(linv, g * 4 + r);
    size_t obase = ((size_t)(b * NN + qb * 64 + w * 16)) * CC + head * 64;
#pragma unroll
    for (int dt = 0; dt < 4; ++dt)
#pragma unroll
        for (int r = 0; r < 4; ++r)
            hout[obase + (size_t)(g * 4 + r) * CC + dt * 16 + li] =
                f2bf(acc[dt][r] * lr[r]);
}

extern "C" void kernel_launch(void* const* d_in, const int* in_sizes, int n_in,
                              void* d_out, int out_size, void* d_ws, size_t ws_size,
                              hipStream_t stream) {
    const float* x     = (const float*)d_in[0];
    const int*   mask  = (const int*)d_in[1];
    const float* wqkv  = (const float*)d_in[2];
    const float* wproj = (const float*)d_in[3];
    const float* bproj = (const float*)d_in[4];
    float* out = (float*)d_out;

    unsigned short* x_bf     = (unsigned short*)d_ws;          // 4096*768
    unsigned short* wqkv_bf  = x_bf + 3145728;                 // 2304*768
    unsigned short* wproj_bf = wqkv_bf + 1769472;              // 768*768
    unsigned short* qkv_bf   = wproj_bf + 589824;              // 4096*2304
    unsigned short* h_bf     = qkv_bf + 9437184;               // 4096*768

    cvt_f32_bf16<<<1536, 256, 0, stream>>>(x, x_bf, 393216);
    cvt_f32_bf16<<<864, 256, 0, stream>>>(wqkv, wqkv_bf, 221184);
    cvt_f32_bf16<<<288, 256, 0, stream>>>(wproj, wproj_bf, 73728);

    // qkv = x @ w_qkv^T -> bf16 (Q columns pre-scaled by SCALE*log2e)
    gemm_bt<<<dim3(18, 32), 256, 0, stream>>>(x_bf, wqkv_bf, qkv_bf, nullptr,
                                              nullptr, 4096, 2304, 768, 768);
    // masked flash attention -> h (B,N,C) bf16
    attn_kernel<<<768, 256, 0, stream>>>(qkv_bf, mask, h_bf);
    // out = h @ w_proj^T + b -> f32
    gemm_bt<<<dim3(6, 32), 256, 0, stream>>>(h_bf, wproj_bf, nullptr, out,
                                             bproj, 4096, 768, 768, 0);
}